// Round 7
// baseline (575.883 us; speedup 1.0000x reference)
//
#include <hip/hip_runtime.h>

#define NB 512
#define SLOTS 32
#define D 1024
#define D4 256           // float4 per row
#define CAP 64
#define TAU_INV 10.0f

// ---- kernel 0: zero the per-bucket counters ----
__global__ void k_zero(int* __restrict__ cnt) {
    if (threadIdx.x < NB) cnt[threadIdx.x] = 0;
}

// ---- kernel 1: build per-bucket token lists (list order nondeterministic;
//      per-token FP math is list-order-invariant → deterministic output) ----
__global__ void k_build(const int* __restrict__ tids, int n,
                        int* __restrict__ cnt, int* __restrict__ list) {
    int i = blockIdx.x * 256 + threadIdx.x;
    if (i < n) {
        int b = tids[i] & (NB - 1);
        int p = atomicAdd(&cnt[b], 1);
        if (p < CAP) list[b * CAP + p] = i;
    }
}

// dot of one key/value row (held in K[4]) against two unified queries
#define DOT4(K, d0, d1)                                                     \
    do {                                                                    \
        d0 = 0.f; d1 = 0.f;                                                 \
        _Pragma("unroll")                                                   \
        for (int j = 0; j < 4; ++j) {                                       \
            d0 += K[j].x*uq0[j].x + K[j].y*uq0[j].y                         \
                + K[j].z*uq0[j].z + K[j].w*uq0[j].w;                        \
            d1 += K[j].x*uq1[j].x + K[j].y*uq1[j].y                         \
                + K[j].z*uq1[j].z + K[j].w*uq1[j].w;                        \
        }                                                                   \
    } while (0)

// ---- kernel 2: barrier-free, wave-autonomous (2 tokens/wave), with
//      explicit 4-row rotating load buffers (16 float4 loads in flight).
//      The ~120-reg live set forces the allocator to ~128 VGPRs — R6's
//      collapse to 64 VGPRs (MLP=2, 145us) cannot recur. No LDS, no syncs.
__global__ __launch_bounds__(256, 2)
void k_main(const float* __restrict__ query,    // [NT][D]
            const int*   __restrict__ tids,     // [NT]
            const float* __restrict__ skeys,    // [NB*SLOTS][D]
            const float* __restrict__ svals,    // [NB*SLOTS][D]
            const int*   __restrict__ stids,    // [NB*SLOTS]
            const float* __restrict__ centroid, // [NB][D]
            float*       __restrict__ out,      // [NT][D]
            const int*   __restrict__ cnt,
            const int*   __restrict__ list)
{
    const int bucket = blockIdx.x & (NB - 1);
    const int h      = blockIdx.x >> 9;        // 0/1
    const int lane   = threadIdx.x & 63;
    const int wid    = threadIdx.x >> 6;       // 0..3
    const int wslot  = h * 4 + wid;            // 0..7

    const int count = min(cnt[bucket], CAP);
    if (count == 0) return;

    const int slot_tid = stids[bucket * SLOTS + (lane & 31)];
    const float4* kb = (const float4*)(skeys + (size_t)bucket * SLOTS * D);
    const float4* vb = (const float4*)(svals + (size_t)bucket * SLOTS * D);
    const float4* cb = (const float4*)(centroid + (size_t)bucket * D);

    float4 anc[4];
    #pragma unroll
    for (int j = 0; j < 4; ++j) anc[j] = cb[lane + 64 * j];

    for (int base = wslot * 2; base < count; base += 16) {
        const int t1ok = (base + 1 < count);
        const int tokA = list[bucket * CAP + base];
        const int tokB = list[bucket * CAP + (t1ok ? base + 1 : base)];
        const int tidA = tids[tokA];
        const int tidB = tids[tokB];

        // ---- unified queries (registers) ----
        float4 uq0[4], uq1[4];
        {
            const float4* qa = (const float4*)(query + (size_t)tokA * D);
            const float4* qb = (const float4*)(query + (size_t)tokB * D);
            float4 qva[4], qvb[4];
            float ssa = 0.f, ssb = 0.f;
            #pragma unroll
            for (int j = 0; j < 4; ++j) {
                qva[j] = qa[lane + 64 * j];
                qvb[j] = qb[lane + 64 * j];
                ssa += qva[j].x*qva[j].x + qva[j].y*qva[j].y + qva[j].z*qva[j].z + qva[j].w*qva[j].w;
                ssb += qvb[j].x*qvb[j].x + qvb[j].y*qvb[j].y + qvb[j].z*qvb[j].z + qvb[j].w*qvb[j].w;
            }
            #pragma unroll
            for (int off = 32; off >= 1; off >>= 1) {
                ssa += __shfl_xor(ssa, off);
                ssb += __shfl_xor(ssb, off);
            }
            const float qna = 0.5f / fmaxf(sqrtf(ssa), 1e-12f);  // folds ALPHA
            const float qnb = 0.5f / fmaxf(sqrtf(ssb), 1e-12f);
            float s2a = 0.f, s2b = 0.f;
            #pragma unroll
            for (int j = 0; j < 4; ++j) {
                uq0[j].x = qva[j].x * qna + 0.5f * anc[j].x;
                uq0[j].y = qva[j].y * qna + 0.5f * anc[j].y;
                uq0[j].z = qva[j].z * qna + 0.5f * anc[j].z;
                uq0[j].w = qva[j].w * qna + 0.5f * anc[j].w;
                uq1[j].x = qvb[j].x * qnb + 0.5f * anc[j].x;
                uq1[j].y = qvb[j].y * qnb + 0.5f * anc[j].y;
                uq1[j].z = qvb[j].z * qnb + 0.5f * anc[j].z;
                uq1[j].w = qvb[j].w * qnb + 0.5f * anc[j].w;
                s2a += uq0[j].x*uq0[j].x + uq0[j].y*uq0[j].y + uq0[j].z*uq0[j].z + uq0[j].w*uq0[j].w;
                s2b += uq1[j].x*uq1[j].x + uq1[j].y*uq1[j].y + uq1[j].z*uq1[j].z + uq1[j].w*uq1[j].w;
            }
            #pragma unroll
            for (int off = 32; off >= 1; off >>= 1) {
                s2a += __shfl_xor(s2a, off);
                s2b += __shfl_xor(s2b, off);
            }
            const float una = 1.0f / fmaxf(sqrtf(s2a), 1e-12f);
            const float unb = 1.0f / fmaxf(sqrtf(s2b), 1e-12f);
            #pragma unroll
            for (int j = 0; j < 4; ++j) {
                uq0[j].x *= una; uq0[j].y *= una; uq0[j].z *= una; uq0[j].w *= una;
                uq1[j].x *= unb; uq1[j].y *= unb; uq1[j].z *= unb; uq1[j].w *= unb;
            }
        }

        // ---- scores: 4-row rotating buffers, 16 loads in flight ----
        float sc0 = 0.f, sc1 = 0.f;
        {
            float4 r0[4], r1[4], r2[4], r3[4];
            #pragma unroll
            for (int j = 0; j < 4; ++j) {
                r0[j] = kb[0 * D4 + lane + 64 * j];
                r1[j] = kb[1 * D4 + lane + 64 * j];
                r2[j] = kb[2 * D4 + lane + 64 * j];
                r3[j] = kb[3 * D4 + lane + 64 * j];
            }
            #pragma unroll
            for (int s = 0; s < SLOTS; s += 4) {
                float a0, a1, b0, b1, c0, c1, e0, e1;
                DOT4(r0, a0, a1);
                DOT4(r1, b0, b1);
                DOT4(r2, c0, c1);
                DOT4(r3, e0, e1);
                if (s + 4 < SLOTS) {
                    #pragma unroll
                    for (int j = 0; j < 4; ++j) {
                        r0[j] = kb[(s + 4) * D4 + lane + 64 * j];
                        r1[j] = kb[(s + 5) * D4 + lane + 64 * j];
                        r2[j] = kb[(s + 6) * D4 + lane + 64 * j];
                        r3[j] = kb[(s + 7) * D4 + lane + 64 * j];
                    }
                }
                #pragma unroll
                for (int off = 32; off >= 1; off >>= 1) {
                    a0 += __shfl_xor(a0, off); a1 += __shfl_xor(a1, off);
                    b0 += __shfl_xor(b0, off); b1 += __shfl_xor(b1, off);
                    c0 += __shfl_xor(c0, off); c1 += __shfl_xor(c1, off);
                    e0 += __shfl_xor(e0, off); e1 += __shfl_xor(e1, off);
                }
                sc0 = (lane == s + 0) ? a0 : sc0;  sc1 = (lane == s + 0) ? a1 : sc1;
                sc0 = (lane == s + 1) ? b0 : sc0;  sc1 = (lane == s + 1) ? b1 : sc1;
                sc0 = (lane == s + 2) ? c0 : sc0;  sc1 = (lane == s + 2) ? c1 : sc1;
                sc0 = (lane == s + 3) ? e0 : sc0;  sc1 = (lane == s + 3) ? e1 : sc1;
            }
        }

        // ---- in-wave softmax + hard-match (slots live in lanes 0..31) ----
        float p0, p1;
        {
            const bool live = (lane < 32);
            float m0 = sc0, m1 = sc1;
            #pragma unroll
            for (int off = 16; off >= 1; off >>= 1) {
                m0 = fmaxf(m0, __shfl_xor(m0, off));
                m1 = fmaxf(m1, __shfl_xor(m1, off));
            }
            float e0 = live ? __expf((sc0 - m0) * TAU_INV) : 0.f;
            float e1 = live ? __expf((sc1 - m1) * TAU_INV) : 0.f;
            float f0 = (live && slot_tid == tidA) ? 1.f : 0.f;
            float f1 = (live && slot_tid == tidB) ? 1.f : 0.f;
            float es0 = e0, es1 = e1, ms0 = f0, ms1 = f1;
            #pragma unroll
            for (int off = 16; off >= 1; off >>= 1) {
                es0 += __shfl_xor(es0, off); es1 += __shfl_xor(es1, off);
                ms0 += __shfl_xor(ms0, off); ms1 += __shfl_xor(ms1, off);
            }
            p0 = (ms0 > 0.f) ? f0 / (ms0 + 1e-9f) : e0 / es0;
            p1 = (ms1 > 0.f) ? f1 / (ms1 + 1e-9f) : e1 / es1;
        }

        // ---- values: same 4-row rotation; both tokens reuse each row ----
        float4 acc0[4], acc1[4];
        #pragma unroll
        for (int j = 0; j < 4; ++j) {
            acc0[j] = make_float4(0.f, 0.f, 0.f, 0.f);
            acc1[j] = make_float4(0.f, 0.f, 0.f, 0.f);
        }
        {
            float4 r0[4], r1[4], r2[4], r3[4];
            #pragma unroll
            for (int j = 0; j < 4; ++j) {
                r0[j] = vb[0 * D4 + lane + 64 * j];
                r1[j] = vb[1 * D4 + lane + 64 * j];
                r2[j] = vb[2 * D4 + lane + 64 * j];
                r3[j] = vb[3 * D4 + lane + 64 * j];
            }
            #pragma unroll
            for (int s = 0; s < SLOTS; s += 4) {
                const float w00 = __shfl(p0, s + 0), w10 = __shfl(p1, s + 0);
                const float w01 = __shfl(p0, s + 1), w11 = __shfl(p1, s + 1);
                const float w02 = __shfl(p0, s + 2), w12 = __shfl(p1, s + 2);
                const float w03 = __shfl(p0, s + 3), w13 = __shfl(p1, s + 3);
                #pragma unroll
                for (int j = 0; j < 4; ++j) {
                    acc0[j].x += w00*r0[j].x + w01*r1[j].x + w02*r2[j].x + w03*r3[j].x;
                    acc0[j].y += w00*r0[j].y + w01*r1[j].y + w02*r2[j].y + w03*r3[j].y;
                    acc0[j].z += w00*r0[j].z + w01*r1[j].z + w02*r2[j].z + w03*r3[j].z;
                    acc0[j].w += w00*r0[j].w + w01*r1[j].w + w02*r2[j].w + w03*r3[j].w;
                    acc1[j].x += w10*r0[j].x + w11*r1[j].x + w12*r2[j].x + w13*r3[j].x;
                    acc1[j].y += w10*r0[j].y + w11*r1[j].y + w12*r2[j].y + w13*r3[j].y;
                    acc1[j].z += w10*r0[j].z + w11*r1[j].z + w12*r2[j].z + w13*r3[j].z;
                    acc1[j].w += w10*r0[j].w + w11*r1[j].w + w12*r2[j].w + w13*r3[j].w;
                }
                if (s + 4 < SLOTS) {
                    #pragma unroll
                    for (int j = 0; j < 4; ++j) {
                        r0[j] = vb[(s + 4) * D4 + lane + 64 * j];
                        r1[j] = vb[(s + 5) * D4 + lane + 64 * j];
                        r2[j] = vb[(s + 6) * D4 + lane + 64 * j];
                        r3[j] = vb[(s + 7) * D4 + lane + 64 * j];
                    }
                }
            }
        }

        float4* oA = (float4*)(out + (size_t)tokA * D);
        #pragma unroll
        for (int j = 0; j < 4; ++j) oA[lane + 64 * j] = acc0[j];
        if (t1ok) {
            float4* oB = (float4*)(out + (size_t)tokB * D);
            #pragma unroll
            for (int j = 0; j < 4; ++j) oB[lane + 64 * j] = acc1[j];
        }
    }
}

extern "C" void kernel_launch(void* const* d_in, const int* in_sizes, int n_in,
                              void* d_out, int out_size, void* d_ws, size_t ws_size,
                              hipStream_t stream) {
    const float* query    = (const float*)d_in[0];
    const int*   tids     = (const int*)  d_in[1];
    const float* skeys    = (const float*)d_in[2];
    const float* svals    = (const float*)d_in[3];
    const int*   stids    = (const int*)  d_in[4];
    const float* centroid = (const float*)d_in[5];
    float* out = (float*)d_out;
    const int n_tokens = in_sizes[1];

    int* cnt  = (int*)d_ws;             // [NB]
    int* list = cnt + NB;               // [NB*CAP]

    k_zero<<<1, NB, 0, stream>>>(cnt);
    k_build<<<(n_tokens + 255) / 256, 256, 0, stream>>>(tids, n_tokens, cnt, list);
    k_main<<<NB * 2, 256, 0, stream>>>(query, tids, skeys, svals, stids,
                                       centroid, out, cnt, list);
}

// Round 8
// 407.303 us; speedup vs baseline: 1.4139x; 1.4139x over previous
//
#include <hip/hip_runtime.h>

#define NB 512
#define SLOTS 32
#define D 1024
#define D4 256           // float4 per row
#define TC 8             // tokens per chunk (== mean bucket load)
#define CAP 64
#define TAU_INV 10.0f
#define BT 512           // 8 waves

// ---- kernel 0: zero per-bucket counters ----
__global__ void k_zero(int* __restrict__ cnt) {
    if (threadIdx.x < NB) cnt[threadIdx.x] = 0;
}

// ---- kernel 1: build per-bucket token lists (list order nondeterministic;
//      per-token FP math is list-order-invariant → deterministic output) ----
__global__ void k_build(const int* __restrict__ tids, int n,
                        int* __restrict__ cnt, int* __restrict__ list) {
    int i = blockIdx.x * 256 + threadIdx.x;
    if (i < n) {
        int b = tids[i] & (NB - 1);
        int p = atomicAdd(&cnt[b], 1);
        if (p < CAP) list[b * CAP + p] = i;
    }
}

// ---- kernel 2: one block per bucket, 8 waves, TC=8 tokens/chunk.
//      Score phase: each wave owns 4 slots; accumulates ALL 32 (t,s) partials
//      in registers, then ONE batched halving-reduce (32 shfl total vs 384
//      for per-value butterflies — the DS-pipe was R5's bottleneck).
__global__ __launch_bounds__(BT, 2)
void k_main(const float* __restrict__ query,    // [NT][D]
            const int*   __restrict__ tids,     // [NT]
            const float* __restrict__ skeys,    // [NB*SLOTS][D]
            const float* __restrict__ svals,    // [NB*SLOTS][D]
            const int*   __restrict__ stids,    // [NB*SLOTS]
            const float* __restrict__ centroid, // [NB][D]
            float*       __restrict__ out,      // [NT][D]
            const int*   __restrict__ cnt,
            const int*   __restrict__ list)
{
    const int bucket = blockIdx.x;
    const int tidx   = threadIdx.x;      // 0..511
    const int lane   = tidx & 63;
    const int wid    = tidx >> 6;        // 0..7

    const int count = min(cnt[bucket], CAP);
    if (count == 0) return;

    __shared__ float s_uq[TC][D];        // 32 KB
    __shared__ float s_scores[TC][SLOTS];
    __shared__ float s_probs[TC][SLOTS];
    __shared__ int   s_tok[TC];
    __shared__ int   s_ttid[TC];

    const int slot_tid = stids[bucket * SLOTS + (lane & 31)];
    const float4* kb = (const float4*)(skeys + (size_t)bucket * SLOTS * D);
    const float4* vb = (const float4*)(svals + (size_t)bucket * SLOTS * D);
    const float4* cb = (const float4*)(centroid + (size_t)bucket * D);

    for (int c0 = 0; c0 < count; c0 += TC) {
        const int nt = min(TC, count - c0);

        // ---- query phase: wave w owns token w (regs only, ~60 VGPR) ----
        if (wid < nt) {
            const int tok = list[bucket * CAP + c0 + wid];
            const float4* q4 = (const float4*)(query + (size_t)tok * D);
            float4 qv[4], anc[4];
            float ss = 0.f;
            #pragma unroll
            for (int j = 0; j < 4; ++j) {
                qv[j]  = q4[lane + 64 * j];
                anc[j] = cb[lane + 64 * j];
                ss += qv[j].x*qv[j].x + qv[j].y*qv[j].y + qv[j].z*qv[j].z + qv[j].w*qv[j].w;
            }
            #pragma unroll
            for (int off = 32; off >= 1; off >>= 1) ss += __shfl_xor(ss, off);
            const float qn = 0.5f / fmaxf(sqrtf(ss), 1e-12f);   // folds ALPHA=0.5
            float4 uv[4];
            float ss2 = 0.f;
            #pragma unroll
            for (int j = 0; j < 4; ++j) {
                uv[j].x = qv[j].x * qn + 0.5f * anc[j].x;
                uv[j].y = qv[j].y * qn + 0.5f * anc[j].y;
                uv[j].z = qv[j].z * qn + 0.5f * anc[j].z;
                uv[j].w = qv[j].w * qn + 0.5f * anc[j].w;
                ss2 += uv[j].x*uv[j].x + uv[j].y*uv[j].y + uv[j].z*uv[j].z + uv[j].w*uv[j].w;
            }
            #pragma unroll
            for (int off = 32; off >= 1; off >>= 1) ss2 += __shfl_xor(ss2, off);
            const float un = 1.0f / fmaxf(sqrtf(ss2), 1e-12f);
            #pragma unroll
            for (int j = 0; j < 4; ++j) {
                ((float4*)s_uq[wid])[lane + 64 * j] =
                    make_float4(uv[j].x*un, uv[j].y*un, uv[j].z*un, uv[j].w*un);
            }
            if (lane == 0) { s_tok[wid] = tok; s_ttid[wid] = tids[tok]; }
        }
        __syncthreads();

        // ---- score phase: wave owns slots [4w,4w+4); P[32] = 8 tokens x 4 slots ----
        {
            const float4* kw = kb + (size_t)(wid * 4) * D4;
            float4 k0[4], k1[4], k2[4], k3[4];
            #pragma unroll
            for (int j = 0; j < 4; ++j) {
                k0[j] = kw[0 * D4 + lane + 64 * j];
                k1[j] = kw[1 * D4 + lane + 64 * j];
                k2[j] = kw[2 * D4 + lane + 64 * j];
                k3[j] = kw[3 * D4 + lane + 64 * j];
            }
            float P[32];
            #pragma unroll
            for (int i = 0; i < 32; ++i) P[i] = 0.f;
            #pragma unroll
            for (int j = 0; j < 4; ++j) {
                #pragma unroll
                for (int t = 0; t < TC; ++t) {
                    const float4 u = ((const float4*)s_uq[t])[lane + 64 * j];
                    P[t*4+0] += u.x*k0[j].x + u.y*k0[j].y + u.z*k0[j].z + u.w*k0[j].w;
                    P[t*4+1] += u.x*k1[j].x + u.y*k1[j].y + u.z*k1[j].z + u.w*k1[j].w;
                    P[t*4+2] += u.x*k2[j].x + u.y*k2[j].y + u.z*k2[j].z + u.w*k2[j].w;
                    P[t*4+3] += u.x*k3[j].x + u.y*k3[j].y + u.z*k3[j].z + u.w*k3[j].w;
                }
            }
            // batched halving-reduce: 32 values over 64 lanes, 32 shfl total.
            // After stage k (o=2^k), lane keeps low ids iff (lane&o)==0 →
            // final: lane l holds id = bitrev5(l&31), duplicated on l^32.
            #pragma unroll
            for (int k = 0; k < 5; ++k) {
                const int o = 1 << k;
                const int half = 16 >> k;
                const bool hi = (lane & o) != 0;
                #pragma unroll
                for (int i = 0; i < half; ++i) {
                    const float send = hi ? P[i] : P[i + half];
                    const float keep = hi ? P[i + half] : P[i];
                    P[i] = keep + __shfl_xor(send, o);
                }
            }
            P[0] += __shfl_xor(P[0], 32);
            if (lane < 32) {
                const int id = ((lane & 1) << 4) | ((lane & 2) << 2) | (lane & 4)
                             | ((lane >> 2) & 2) | ((lane >> 4) & 1);
                s_scores[id >> 2][wid * 4 + (id & 3)] = P[0];
            }
        }
        __syncthreads();

        // ---- softmax + hard-match: wave w owns token w, lanes 0..31 ----
        if (wid < nt && lane < 32) {
            const float sc = s_scores[wid][lane];
            float m = sc;
            #pragma unroll
            for (int off = 16; off >= 1; off >>= 1) m = fmaxf(m, __shfl_xor(m, off));
            const float e = __expf((sc - m) * TAU_INV);
            const float f = (slot_tid == s_ttid[wid]) ? 1.f : 0.f;
            float es = e, ms = f;
            #pragma unroll
            for (int off = 16; off >= 1; off >>= 1) {
                es += __shfl_xor(es, off);
                ms += __shfl_xor(ms, off);
            }
            s_probs[wid][lane] = (ms > 0.f) ? f / (ms + 1e-9f) : e / es;
        }
        __syncthreads();

        // ---- value phase: wave w owns token w; 4-row rotating prefetch ----
        if (wid < nt) {
            float4 acc[4];
            #pragma unroll
            for (int j = 0; j < 4; ++j) acc[j] = make_float4(0.f, 0.f, 0.f, 0.f);
            float4 r0[4], r1[4], r2[4], r3[4];
            #pragma unroll
            for (int j = 0; j < 4; ++j) {
                r0[j] = vb[0 * D4 + lane + 64 * j];
                r1[j] = vb[1 * D4 + lane + 64 * j];
                r2[j] = vb[2 * D4 + lane + 64 * j];
                r3[j] = vb[3 * D4 + lane + 64 * j];
            }
            #pragma unroll
            for (int s = 0; s < SLOTS; s += 4) {
                const float w0 = s_probs[wid][s + 0];   // LDS broadcast
                const float w1 = s_probs[wid][s + 1];
                const float w2 = s_probs[wid][s + 2];
                const float w3 = s_probs[wid][s + 3];
                #pragma unroll
                for (int j = 0; j < 4; ++j) {
                    acc[j].x += w0*r0[j].x + w1*r1[j].x + w2*r2[j].x + w3*r3[j].x;
                    acc[j].y += w0*r0[j].y + w1*r1[j].y + w2*r2[j].y + w3*r3[j].y;
                    acc[j].z += w0*r0[j].z + w1*r1[j].z + w2*r2[j].z + w3*r3[j].z;
                    acc[j].w += w0*r0[j].w + w1*r1[j].w + w2*r2[j].w + w3*r3[j].w;
                }
                if (s + 4 < SLOTS) {
                    #pragma unroll
                    for (int j = 0; j < 4; ++j) {
                        r0[j] = vb[(s + 4) * D4 + lane + 64 * j];
                        r1[j] = vb[(s + 5) * D4 + lane + 64 * j];
                        r2[j] = vb[(s + 6) * D4 + lane + 64 * j];
                        r3[j] = vb[(s + 7) * D4 + lane + 64 * j];
                    }
                }
            }
            float4* o4 = (float4*)(out + (size_t)s_tok[wid] * D);
            #pragma unroll
            for (int j = 0; j < 4; ++j) o4[lane + 64 * j] = acc[j];
        }
        // no trailing barrier needed: next chunk's writes (s_uq[w], s_tok[w])
        // touch only wave-w-owned rows; s_scores/s_probs rewrites are fenced
        // by sync1/sync2 of the next iteration.
    }
}

extern "C" void kernel_launch(void* const* d_in, const int* in_sizes, int n_in,
                              void* d_out, int out_size, void* d_ws, size_t ws_size,
                              hipStream_t stream) {
    const float* query    = (const float*)d_in[0];
    const int*   tids     = (const int*)  d_in[1];
    const float* skeys    = (const float*)d_in[2];
    const float* svals    = (const float*)d_in[3];
    const int*   stids    = (const int*)  d_in[4];
    const float* centroid = (const float*)d_in[5];
    float* out = (float*)d_out;
    const int n_tokens = in_sizes[1];

    int* cnt  = (int*)d_ws;             // [NB]
    int* list = cnt + NB;               // [NB*CAP]

    k_zero<<<1, BT, 0, stream>>>(cnt);
    k_build<<<(n_tokens + 255) / 256, 256, 0, stream>>>(tids, n_tokens, cnt, list);
    k_main<<<NB, BT, 0, stream>>>(query, tids, skeys, svals, stids,
                                  centroid, out, cnt, list);
}